// Round 6
// baseline (67.317 us; speedup 1.0000x reference)
//
#include <hip/hip_runtime.h>
#include <math.h>

struct Pose {
    float M[9], Tt[3], pR[9], pt[3], gR[9], gt[3], qn;
};

__device__ __forceinline__ float smooth_l1f(float x, float y) {
    float d = fabsf(x - y);
    return d < 1.0f ? 0.5f * d * d : d - 0.5f;
}

// row-major 3x3 -> quaternion, matching the reference's branch selection
// (tr>0 -> case 0, else 1+argmax(diag) with first-max tie-break)
__device__ void mat2quat_dev(const float* R, float* q) {
    float R00=R[0],R01=R[1],R02=R[2];
    float R10=R[3],R11=R[4],R12=R[5];
    float R20=R[6],R21=R[7],R22=R[8];
    float tr = R00 + R11 + R22;
    float t;
    if (tr > 0.0f) {
        t = 1.0f + tr;
        q[0]=t; q[1]=R21-R12; q[2]=R02-R20; q[3]=R10-R01;
    } else {
        int sel = 1; float best = R00;
        if (R11 > best) { sel = 2; best = R11; }
        if (R22 > best) { sel = 3; }
        if (sel == 1)      { t = 1.0f+R00-R11-R22; q[0]=R21-R12; q[1]=t; q[2]=R01+R10; q[3]=R02+R20; }
        else if (sel == 2) { t = 1.0f-R00+R11-R22; q[0]=R02-R20; q[1]=R01+R10; q[2]=t; q[3]=R12+R21; }
        else               { t = 1.0f-R00-R11+R22; q[0]=R10-R01; q[1]=R02+R20; q[2]=R12+R21; q[3]=t; }
    }
    float s = 0.5f / sqrtf(fmaxf(t, 1e-12f));
    q[0]*=s; q[1]*=s; q[2]*=s; q[3]*=s;
}

// All the small per-batch matrix algebra: fused transform for the point loss
// (M = gR^T*pR - I, Tt = gR^T*(pt-gt)) plus intermediates for t/r/qn terms.
__device__ void compute_pose(int b,
                             const float* __restrict__ pred_t,
                             const float* __restrict__ pred_q,
                             const float* __restrict__ gtT,
                             const float* __restrict__ initT,
                             Pose& P)
{
    float tx=pred_t[b*3+0], ty=pred_t[b*3+1], tz=pred_t[b*3+2];
    float q0=pred_q[b*4+0], q1=pred_q[b*4+1], q2=pred_q[b*4+2], q3=pred_q[b*4+3];
    float nsq = q0*q0+q1*q1+q2*q2+q3*q3;
    P.qn = (nsq-1.0f)*(nsq-1.0f);
    float inv = rsqrtf(nsq);
    float w=q0*inv, x=q1*inv, y=q2*inv, z=q3*inv;
    float R[9];
    R[0]=1.0f-2.0f*(y*y+z*z); R[1]=2.0f*(x*y-w*z);      R[2]=2.0f*(x*z+w*y);
    R[3]=2.0f*(x*y+w*z);      R[4]=1.0f-2.0f*(x*x+z*z); R[5]=2.0f*(y*z-w*x);
    R[6]=2.0f*(x*z-w*y);      R[7]=2.0f*(y*z+w*x);      R[8]=1.0f-2.0f*(x*x+y*y);

    float iR[9], it[3];
    for (int i=0;i<3;i++){
        for (int j=0;j<3;j++){
            iR[i*3+j]=initT[b*16+i*4+j];
            P.gR[i*3+j]=gtT[b*16+i*4+j];
        }
        it[i]=initT[b*16+i*4+3];
        P.gt[i]=gtT[b*16+i*4+3];
    }
    // inv(T_pred) @ init : pR = R^T iR, pt = R^T (it - t)
    for (int i=0;i<3;i++){
        for (int j=0;j<3;j++)
            P.pR[i*3+j] = R[0+i]*iR[0+j] + R[3+i]*iR[3+j] + R[6+i]*iR[6+j];
        P.pt[i] = R[0+i]*(it[0]-tx) + R[3+i]*(it[1]-ty) + R[6+i]*(it[2]-tz);
    }
    // RT = inv(gt) @ [pR pt] : M = gR^T pR - I, Tt = gR^T (pt - gt)
    for (int i=0;i<3;i++){
        for (int j=0;j<3;j++)
            P.M[i*3+j] = P.gR[0+i]*P.pR[0+j] + P.gR[3+i]*P.pR[3+j] + P.gR[6+i]*P.pR[6+j];
        P.Tt[i] = P.gR[0+i]*(P.pt[0]-P.gt[0]) + P.gR[3+i]*(P.pt[1]-P.gt[1]) + P.gR[6+i]*(P.pt[2]-P.gt[2]);
    }
    P.M[0]-=1.0f; P.M[4]-=1.0f; P.M[8]-=1.0f;   // pts - pcs = M*p + Tt
}

#define TP  1024  // points per tile
#define F4T 768   // float4s of pcs per tile (TP*3/4)

// Single fused kernel. Streaming part identical to R5 (unit-stride float4
// staged to double-buffered LDS, mask int4 in registers, conflict-free
// ds_read_b128 at 48B lane stride). Each block publishes its partial pair
// via device-coherent atomicExch (atomics bypass the non-coherent per-XCD
// L2s), fences, bumps a counter; the last block pulls all slots back with
// atomic loads (atomicAdd(p, 0.0f)) and finishes the loss inline -> no
// second kernel launch; finish overlaps the grid drain.
__global__ __launch_bounds__(256) void pc_all(const float* __restrict__ pcs,
                                              const int* __restrict__ mask,
                                              const float* __restrict__ pred_t,
                                              const float* __restrict__ pred_q,
                                              const float* __restrict__ gtT,
                                              const float* __restrict__ initT,
                                              unsigned* __restrict__ counter,
                                              float* __restrict__ errS,
                                              float* __restrict__ maskS,
                                              float* __restrict__ out,
                                              int N, int bpb, int chunk, int B)
{
    int bid = blockIdx.x;
    int b   = bid / bpb;
    int blk = bid - b*bpb;
    int t   = threadIdx.x;

    __shared__ float sMT[12];
    __shared__ float sP[2][F4T*4];   // 2 x 12 KB (reused by finish phase)
    __shared__ float sE[4], sM[4];
    __shared__ int   sLast;

    float esum = 0.0f, msum = 0.0f;
    int r0 = blk * chunk;

    if (r0 < N) {
        int my_pts = N - r0; if (my_pts > chunk) my_pts = chunk;   // mult of 4
        int nt    = (my_pts + TP - 1) / TP;
        int my_f4 = (my_pts * 3) >> 2;
        int my_m4 = my_pts >> 2;

        const float4* pf4 = (const float4*)pcs  + ((size_t)b*N + r0)*3/4;
        const int4*   mi4 = (const int4*)  mask + ((size_t)b*N + r0)/4;

        float4 rA = make_float4(0,0,0,0);
        float4 rB = make_float4(0,0,0,0);
        float4 rC = make_float4(0,0,0,0);
        int4   rM = make_int4(0,0,0,0);

        auto stage = [&](int ti) {
            int fb = ti * F4T;
            if (ti*TP + TP <= my_pts) {          // full tile: no guards
                rA = pf4[fb       + t];
                rB = pf4[fb + 256 + t];
                rC = pf4[fb + 512 + t];
                rM = mi4[ti*256 + t];
            } else {
                int s0 = fb + t, s1 = fb + 256 + t, s2 = fb + 512 + t, sm = ti*256 + t;
                rA = (s0 < my_f4) ? pf4[s0] : make_float4(0,0,0,0);
                rB = (s1 < my_f4) ? pf4[s1] : make_float4(0,0,0,0);
                rC = (s2 < my_f4) ? pf4[s2] : make_float4(0,0,0,0);
                rM = (sm < my_m4) ? mi4[sm] : make_int4(0,0,0,0);
            }
        };
        auto wr = [&](int buf) {
            float4* d = (float4*)sP[buf];
            d[t      ] = rA;
            d[t + 256] = rB;
            d[t + 512] = rC;
        };

        stage(0);                        // loads in flight while pose computes
        if (t == 0) {
            Pose P;
            compute_pose(b, pred_t, pred_q, gtT, initT, P);
            #pragma unroll
            for (int k=0;k<9;k++) sMT[k]=P.M[k];
            sMT[9]=P.Tt[0]; sMT[10]=P.Tt[1]; sMT[11]=P.Tt[2];
        }
        __syncthreads();                 // sMT ready
        float m00=sMT[0], m01=sMT[1], m02=sMT[2];
        float m10=sMT[3], m11=sMT[4], m12=sMT[5];
        float m20=sMT[6], m21=sMT[7], m22=sMT[8];
        float t0 =sMT[9], t1 =sMT[10], t2 =sMT[11];
        wr(0);
        __syncthreads();                 // buf0 ready

        for (int ti = 0; ti < nt; ti++) {
            int cur = ti & 1;
            int4 cM = rM;                        // current tile's mask
            if (ti + 1 < nt) stage(ti + 1);      // issue next tile's loads early

            const float4* sp4 = (const float4*)sP[cur];
            float4 A = sp4[3*t], C = sp4[3*t+1], D = sp4[3*t+2];  // 3x ds_read_b128
            float px[4] = {A.x, A.w, C.z, D.y};
            float py[4] = {A.y, C.x, C.w, D.z};
            float pz[4] = {A.z, C.y, D.x, D.w};
            float mf[4] = {(float)cM.x, (float)cM.y, (float)cM.z, (float)cM.w};
            #pragma unroll
            for (int j=0;j<4;j++){
                float dx = fmaf(m00,px[j], fmaf(m01,py[j], fmaf(m02,pz[j], t0)));
                float dy = fmaf(m10,px[j], fmaf(m11,py[j], fmaf(m12,pz[j], t1)));
                float dz = fmaf(m20,px[j], fmaf(m21,py[j], fmaf(m22,pz[j], t2)));
                esum = fmaf(mf[j], sqrtf(fmaf(dx,dx, fmaf(dy,dy, dz*dz))), esum);
                msum += mf[j];
            }

            if (ti + 1 < nt) wr(cur ^ 1);        // write-late into other buffer
            __syncthreads();
        }
    }

    // block reduce + publish + last-block election
    for (int off=32; off>0; off>>=1){
        esum += __shfl_down(esum, off);
        msum += __shfl_down(msum, off);
    }
    int lane = t & 63, wid = t >> 6;
    if (lane==0){ sE[wid]=esum; sM[wid]=msum; }
    __syncthreads();
    if (t==0){
        atomicExch(&errS [bid], sE[0]+sE[1]+sE[2]+sE[3]);   // coherent publish
        atomicExch(&maskS[bid], sM[0]+sM[1]+sM[2]+sM[3]);
        __threadfence();                                    // order exch < counter
        unsigned old = atomicAdd(counter, 1u);
        sLast = (old == (unsigned)(gridDim.x - 1)) ? 1 : 0;
    }
    __syncthreads();
    if (!sLast) return;

    // ===== finish phase (one block) =====
    // group g = batch (32 threads each, B <= 8); atomic loads see all slots.
    int g = t >> 5, sub = t & 31;
    double e = 0.0, m = 0.0;
    if (g < B) {
        for (int k = sub; k < bpb; k += 32) {
            e += (double)atomicAdd(&errS [g*bpb + k], 0.0f);
            m += (double)atomicAdd(&maskS[g*bpb + k], 0.0f);
        }
    }
    double* dE = (double*)&sP[0][0];   // reuse dead LDS (256 doubles)
    double* dM = dE + 256;
    dE[t] = e; dM[t] = m;
    __syncthreads();

    float partial = 0.0f;
    if (t < B) {
        double te = 0.0, tm = 0.0;
        for (int j = 0; j < 32; j++){ te += dE[t*32 + j]; tm += dM[t*32 + j]; }
        Pose P;
        compute_pose(t, pred_t, pred_q, gtT, initT, P);
        float t_term = smooth_l1f(P.pt[0],P.gt[0]) + smooth_l1f(P.pt[1],P.gt[1])
                     + smooth_l1f(P.pt[2],P.gt[2]);
        float qp[4], qg[4];
        mat2quat_dev(P.pR,qp); mat2quat_dev(P.gR,qg);
        float dw  = qp[0]*qg[0] + qp[1]*qg[1] + qp[2]*qg[2] + qp[3]*qg[3];
        float cx  = qp[2]*qg[3]-qp[3]*qg[2];
        float cy  = qp[3]*qg[1]-qp[1]*qg[3];
        float cz  = qp[1]*qg[2]-qp[2]*qg[1];
        float dvx = -qp[0]*qg[1] + qg[0]*qp[1] - cx;
        float dvy = -qp[0]*qg[2] + qg[0]*qp[2] - cy;
        float dvz = -qp[0]*qg[3] + qg[0]*qp[3] - cz;
        float r_term = 2.0f*atan2f(sqrtf(dvx*dvx+dvy*dvy+dvz*dvz), fabsf(dw));
        partial = (1.0f*t_term + 0.5f*r_term + 0.5f*P.qn) / (float)B
                + (float)(0.5 * (te / tm) / (double)B);
    }
    if (t < 64) {
        for (int off=32; off>0; off>>=1) partial += __shfl_down(partial, off);
        if (t==0) out[0] = partial;
    }
}

extern "C" void kernel_launch(void* const* d_in, const int* in_sizes, int n_in,
                              void* d_out, int out_size, void* d_ws, size_t ws_size,
                              hipStream_t stream)
{
    const float* pred_t = (const float*)d_in[0];
    const float* pred_q = (const float*)d_in[1];
    const float* pcs    = (const float*)d_in[2];
    const float* gtT    = (const float*)d_in[3];
    const float* initT  = (const float*)d_in[4];
    const int*   mask   = (const int*)d_in[5];

    int B = in_sizes[0] / 3;
    int N = in_sizes[2] / (B * 3);

    int bpb   = 192;                                   // 6 blocks/CU at ~24.2 KB LDS
    int chunk = (((N + bpb - 1) / bpb) + 3) & ~3;      // points/block, mult of 4
    int grid  = B * bpb;                               // 1536 = exactly 6/CU

    unsigned* counter = (unsigned*)d_ws;               // [1], zeroed per call
    float*    errS    = (float*)d_ws + 64;             // [grid]
    float*    maskS   = errS + grid;                   // [grid]
    float*    out     = (float*)d_out;

    hipMemsetAsync(counter, 0, sizeof(unsigned), stream);   // capture-legal memset node
    pc_all<<<grid, 256, 0, stream>>>(pcs, mask, pred_t, pred_q, gtT, initT,
                                     counter, errS, maskS, out, N, bpb, chunk, B);
}

// Round 7
// 27.816 us; speedup vs baseline: 2.4201x; 2.4201x over previous
//
#include <hip/hip_runtime.h>
#include <math.h>

struct Pose {
    float M[9], Tt[3], pR[9], pt[3], gR[9], gt[3], qn;
};

__device__ __forceinline__ float smooth_l1f(float x, float y) {
    float d = fabsf(x - y);
    return d < 1.0f ? 0.5f * d * d : d - 0.5f;
}

// row-major 3x3 -> quaternion, matching the reference's branch selection
// (tr>0 -> case 0, else 1+argmax(diag) with first-max tie-break)
__device__ void mat2quat_dev(const float* R, float* q) {
    float R00=R[0],R01=R[1],R02=R[2];
    float R10=R[3],R11=R[4],R12=R[5];
    float R20=R[6],R21=R[7],R22=R[8];
    float tr = R00 + R11 + R22;
    float t;
    if (tr > 0.0f) {
        t = 1.0f + tr;
        q[0]=t; q[1]=R21-R12; q[2]=R02-R20; q[3]=R10-R01;
    } else {
        int sel = 1; float best = R00;
        if (R11 > best) { sel = 2; best = R11; }
        if (R22 > best) { sel = 3; }
        if (sel == 1)      { t = 1.0f+R00-R11-R22; q[0]=R21-R12; q[1]=t; q[2]=R01+R10; q[3]=R02+R20; }
        else if (sel == 2) { t = 1.0f-R00+R11-R22; q[0]=R02-R20; q[1]=R01+R10; q[2]=t; q[3]=R12+R21; }
        else               { t = 1.0f-R00-R11+R22; q[0]=R10-R01; q[1]=R02+R20; q[2]=R12+R21; q[3]=t; }
    }
    float s = 0.5f / sqrtf(fmaxf(t, 1e-12f));
    q[0]*=s; q[1]*=s; q[2]*=s; q[3]*=s;
}

// All the small per-batch matrix algebra: fused transform for the point loss
// (M = gR^T*pR - I, Tt = gR^T*(pt-gt)) plus intermediates for t/r/qn terms.
__device__ void compute_pose(int b,
                             const float* __restrict__ pred_t,
                             const float* __restrict__ pred_q,
                             const float* __restrict__ gtT,
                             const float* __restrict__ initT,
                             Pose& P)
{
    float tx=pred_t[b*3+0], ty=pred_t[b*3+1], tz=pred_t[b*3+2];
    float q0=pred_q[b*4+0], q1=pred_q[b*4+1], q2=pred_q[b*4+2], q3=pred_q[b*4+3];
    float nsq = q0*q0+q1*q1+q2*q2+q3*q3;
    P.qn = (nsq-1.0f)*(nsq-1.0f);
    float inv = rsqrtf(nsq);
    float w=q0*inv, x=q1*inv, y=q2*inv, z=q3*inv;
    float R[9];
    R[0]=1.0f-2.0f*(y*y+z*z); R[1]=2.0f*(x*y-w*z);      R[2]=2.0f*(x*z+w*y);
    R[3]=2.0f*(x*y+w*z);      R[4]=1.0f-2.0f*(x*x+z*z); R[5]=2.0f*(y*z-w*x);
    R[6]=2.0f*(x*z-w*y);      R[7]=2.0f*(y*z+w*x);      R[8]=1.0f-2.0f*(x*x+y*y);

    float iR[9], it[3];
    for (int i=0;i<3;i++){
        for (int j=0;j<3;j++){
            iR[i*3+j]=initT[b*16+i*4+j];
            P.gR[i*3+j]=gtT[b*16+i*4+j];
        }
        it[i]=initT[b*16+i*4+3];
        P.gt[i]=gtT[b*16+i*4+3];
    }
    // inv(T_pred) @ init : pR = R^T iR, pt = R^T (it - t)
    for (int i=0;i<3;i++){
        for (int j=0;j<3;j++)
            P.pR[i*3+j] = R[0+i]*iR[0+j] + R[3+i]*iR[3+j] + R[6+i]*iR[6+j];
        P.pt[i] = R[0+i]*(it[0]-tx) + R[3+i]*(it[1]-ty) + R[6+i]*(it[2]-tz);
    }
    // RT = inv(gt) @ [pR pt] : M = gR^T pR - I, Tt = gR^T (pt - gt)
    for (int i=0;i<3;i++){
        for (int j=0;j<3;j++)
            P.M[i*3+j] = P.gR[0+i]*P.pR[0+j] + P.gR[3+i]*P.pR[3+j] + P.gR[6+i]*P.pR[6+j];
        P.Tt[i] = P.gR[0+i]*(P.pt[0]-P.gt[0]) + P.gR[3+i]*(P.pt[1]-P.gt[1]) + P.gR[6+i]*(P.pt[2]-P.gt[2]);
    }
    P.M[0]-=1.0f; P.M[4]-=1.0f; P.M[8]-=1.0f;   // pts - pcs = M*p + Tt
}

// scalar (t/r/qn) loss terms for one batch, already divided by B
__device__ float scalar_terms(const Pose& P, int B) {
    float t_term = smooth_l1f(P.pt[0],P.gt[0]) + smooth_l1f(P.pt[1],P.gt[1])
                 + smooth_l1f(P.pt[2],P.gt[2]);
    float qp[4], qg[4];
    mat2quat_dev(P.pR,qp); mat2quat_dev(P.gR,qg);
    float dw  = qp[0]*qg[0] + qp[1]*qg[1] + qp[2]*qg[2] + qp[3]*qg[3];
    float cx  = qp[2]*qg[3]-qp[3]*qg[2];
    float cy  = qp[3]*qg[1]-qp[1]*qg[3];
    float cz  = qp[1]*qg[2]-qp[2]*qg[1];
    float dvx = -qp[0]*qg[1] + qg[0]*qp[1] - cx;
    float dvy = -qp[0]*qg[2] + qg[0]*qp[2] - cy;
    float dvz = -qp[0]*qg[3] + qg[0]*qp[3] - cz;
    float r_term = 2.0f*atan2f(sqrtf(dvx*dvx+dvy*dvy+dvz*dvz), fabsf(dw));
    return (1.0f*t_term + 0.5f*r_term + 0.5f*P.qn) / (float)B;
}

#define TP  512   // points per tile
#define F4T 384   // float4s of pcs per tile (TP*3/4)
#define M4T 128   // int4s of mask per tile (TP/4)

// Streaming kernel (R4 structure - best measured): unit-stride float4/int4
// loads, register-prefetched double-buffered LDS, 1 barrier/tile,
// conflict-free stride-3-dword LDS reads. Each block writes ONE float2
// partial (err,mask) to its own slot; block 0 of each batch also computes
// the scalar pose terms (hidden under streaming) so the finish kernel is a
// pure reduction. NOTE (R6 lesson): do NOT fuse the finish via a global
// atomic counter - 1536 same-line RMWs + per-block threadfence doubled
// total time on this chip.
__global__ __launch_bounds__(256) void pc_fused(const float* __restrict__ pcs,
                                                const int* __restrict__ mask,
                                                const float* __restrict__ pred_t,
                                                const float* __restrict__ pred_q,
                                                const float* __restrict__ gtT,
                                                const float* __restrict__ initT,
                                                float2* __restrict__ partS,
                                                float* __restrict__ scalarS,
                                                int N, int bpb, int chunk, int B)
{
    int b   = blockIdx.x / bpb;
    int blk = blockIdx.x - b*bpb;
    int t   = threadIdx.x;

    __shared__ float sMT[12];
    __shared__ float sP[2][F4T*4];   // 2 x 6 KB
    __shared__ float sK[2][TP];      // 2 x 2 KB
    __shared__ float sE[4], sM[4];

    int r0 = blk * chunk;
    if (r0 >= N) {   // defensive; not hit with current shapes
        if (t==0) partS[blockIdx.x] = make_float2(0.0f, 0.0f);
        return;
    }
    int my_pts = N - r0; if (my_pts > chunk) my_pts = chunk;   // multiple of 4
    int nt    = (my_pts + TP - 1) / TP;
    int my_f4 = (my_pts * 3) >> 2;
    int my_m4 = my_pts >> 2;

    const float4* pf4 = (const float4*)pcs  + ((size_t)b*N + r0)*3/4;
    const int4*   mi4 = (const int4*)  mask + ((size_t)b*N + r0)/4;

    if (t == 0) {
        Pose P;
        compute_pose(b, pred_t, pred_q, gtT, initT, P);
        #pragma unroll
        for (int k=0;k<9;k++) sMT[k]=P.M[k];
        sMT[9]=P.Tt[0]; sMT[10]=P.Tt[1]; sMT[11]=P.Tt[2];
        if (blk == 0) scalarS[b] = scalar_terms(P, B);   // hidden under streaming
    }

    float4 rA = make_float4(0,0,0,0);
    float4 rB = make_float4(0,0,0,0);
    float4 rM = make_float4(0,0,0,0);

    auto stage = [&](int ti) {
        int fbase = ti * F4T;
        bool full = (ti*TP + TP <= my_pts);
        if (full) {
            rA = pf4[fbase + t];
            if (t < 128) {
                rB = pf4[fbase + 256 + t];
                int4 m = mi4[ti*M4T + t];
                rM = make_float4((float)m.x,(float)m.y,(float)m.z,(float)m.w);
            }
        } else {
            int s0 = fbase + t;
            rA = (s0 < my_f4) ? pf4[s0] : make_float4(0,0,0,0);
            if (t < 128) {
                int s1 = fbase + 256 + t;
                rB = (s1 < my_f4) ? pf4[s1] : make_float4(0,0,0,0);
                int s2 = ti*M4T + t;
                if (s2 < my_m4) {
                    int4 m = mi4[s2];
                    rM = make_float4((float)m.x,(float)m.y,(float)m.z,(float)m.w);
                } else rM = make_float4(0,0,0,0);
            }
        }
    };
    auto wr = [&](int buf) {
        ((float4*)sP[buf])[t] = rA;
        if (t < 128) {
            ((float4*)sP[buf])[256 + t] = rB;
            ((float4*)sK[buf])[t]       = rM;
        }
    };

    stage(0);
    __syncthreads();                 // sMT ready
    float m00=sMT[0], m01=sMT[1], m02=sMT[2];
    float m10=sMT[3], m11=sMT[4], m12=sMT[5];
    float m20=sMT[6], m21=sMT[7], m22=sMT[8];
    float t0 =sMT[9], t1 =sMT[10], t2 =sMT[11];
    wr(0);
    __syncthreads();                 // buf0 ready

    float esum = 0.0f, msum = 0.0f;
    for (int ti = 0; ti < nt; ti++) {
        int cur = ti & 1;
        if (ti + 1 < nt) stage(ti + 1);      // issue next tile's loads early
        #pragma unroll
        for (int k = 0; k < 2; k++) {
            int p = t + (k << 8);            // 0..511, conflict-free stride-3 reads
            float x = sP[cur][3*p], y = sP[cur][3*p+1], z = sP[cur][3*p+2];
            float mm = sK[cur][p];
            float dx = fmaf(m00,x, fmaf(m01,y, fmaf(m02,z, t0)));
            float dy = fmaf(m10,x, fmaf(m11,y, fmaf(m12,z, t1)));
            float dz = fmaf(m20,x, fmaf(m21,y, fmaf(m22,z, t2)));
            esum = fmaf(mm, sqrtf(fmaf(dx,dx, fmaf(dy,dy, dz*dz))), esum);
            msum += mm;
        }
        if (ti + 1 < nt) wr(cur ^ 1);        // write-late into the other buffer
        __syncthreads();                     // one barrier per tile
    }

    for (int off=32; off>0; off>>=1){
        esum += __shfl_down(esum, off);
        msum += __shfl_down(msum, off);
    }
    int lane = t & 63, wid = t >> 6;
    if (lane==0){ sE[wid]=esum; sM[wid]=msum; }
    __syncthreads();
    if (t==0)
        partS[blockIdx.x] = make_float2(sE[0]+sE[1]+sE[2]+sE[3],
                                        sM[0]+sM[1]+sM[2]+sM[3]);
}

// Pure reduction: 32 threads per batch, 8 contiguous float2 slots each
// (coalesced), shfl-reduce within the 32-group, then one thread combines
// with the precomputed scalar terms.
__global__ void finish_kernel(const float2* __restrict__ partS,
                              const float* __restrict__ scalarS,
                              float* __restrict__ out, int B, int bpb)
{
    int t = threadIdx.x;            // 256 threads
    int g = t >> 5, sub = t & 31;   // batch group, lane-in-group
    int per = bpb / 32;             // slots per thread (8 for bpb=256)
    __shared__ double sPC[8];

    float e = 0.0f, m = 0.0f;
    if (g < B) {
        const float2* base = partS + (size_t)g*bpb + sub*per;
        for (int k = 0; k < per; k++) { float2 v = base[k]; e += v.x; m += v.y; }
    }
    for (int off=16; off>0; off>>=1){
        e += __shfl_down(e, off, 32);
        m += __shfl_down(m, off, 32);
    }
    if (sub == 0 && g < B) sPC[g] = (double)e / (double)m;
    __syncthreads();
    if (t == 0) {
        double pc = 0.0; float sc = 0.0f;
        for (int b=0;b<B;b++){ pc += sPC[b]; sc += scalarS[b]; }
        out[0] = sc + 0.5f * (float)(pc / (double)B);
    }
}

extern "C" void kernel_launch(void* const* d_in, const int* in_sizes, int n_in,
                              void* d_out, int out_size, void* d_ws, size_t ws_size,
                              hipStream_t stream)
{
    const float* pred_t = (const float*)d_in[0];
    const float* pred_q = (const float*)d_in[1];
    const float* pcs    = (const float*)d_in[2];
    const float* gtT    = (const float*)d_in[3];
    const float* initT  = (const float*)d_in[4];
    const int*   mask   = (const int*)d_in[5];

    int B = in_sizes[0] / 3;
    int N = in_sizes[2] / (B * 3);

    int bpb   = 256;                                   // blocks per batch
    int chunk = (((N + bpb - 1) / bpb) + 3) & ~3;      // points/block, mult of 4
    int grid  = B * bpb;

    float2* partS   = (float2*)d_ws;                   // [grid], always written
    float*  scalarS = (float*)(partS + grid);          // [B], always written
    float*  out     = (float*)d_out;

    pc_fused<<<grid, 256, 0, stream>>>(pcs, mask, pred_t, pred_q, gtT, initT,
                                       partS, scalarS, N, bpb, chunk, B);
    finish_kernel<<<1, 256, 0, stream>>>(partS, scalarS, out, B, bpb);
}